// Round 10
// baseline (204.027 us; speedup 1.0000x reference)
//
#include <hip/hip_runtime.h>
#include <hip/hip_bf16.h>

#define F_IN   64
#define KF     256    // K * F_OUT
#define BSHIFT 7      // bucket = row >> 7  (128 rows per bucket)
#define BROWS  128
#define MAXBUK 1024   // supports N up to 131072
#define SB     512    // stats blocks inside K1
#define BPB    1024   // edges per binpass block (4 per thread)

typedef __attribute__((ext_vector_type(8))) short short8v;
typedef __attribute__((ext_vector_type(4))) float float4v;

__device__ __forceinline__ float bfbits2f(unsigned short u) {
    union { unsigned i; float f; } x; x.i = ((unsigned)u) << 16; return x.f;
}
__device__ __forceinline__ unsigned short f2bf(float f) {   // RNE
    unsigned u = __float_as_uint(f);
    return (unsigned short)((u + 0x7FFF + ((u >> 16) & 1)) >> 16);
}

// ---------------------------------------------------------------------------
// K1 (fused): blocks [0,SB) = BatchNorm stats; blocks [SB,SB+CHB) = coarse
// histogram of edges per 128-row bucket.  Independent inputs -> max() time.
// ---------------------------------------------------------------------------
__global__ __launch_bounds__(256) void k1_stats_chist(
    const float* __restrict__ a, float* __restrict__ stats, int N,
    const int* __restrict__ rows, int* __restrict__ ccnt, int E, int nbuk)
{
    __shared__ int shm[MAXBUK];          // stats: 512 floats; chist: nbuk ints
    const int tid = threadIdx.x;
    if ((int)blockIdx.x < SB) {
        float* ssum = (float*)shm;
        float* ssq  = ((float*)shm) + 256;
        const int c = tid & 63;
        int r = blockIdx.x * 4 + (tid >> 6);
        const int rstride = SB * 4;
        float ps = 0.f, pq = 0.f;
        for (; r < N; r += rstride) {
            float v = a[(size_t)r * F_IN + c];
            ps += v;
            pq += v * v;
        }
        ssum[tid] = ps;
        ssq[tid]  = pq;
        __syncthreads();
        if (tid < 64) {
            float s = ssum[tid] + ssum[tid + 64] + ssum[tid + 128] + ssum[tid + 192];
            float q = ssq[tid]  + ssq[tid + 64]  + ssq[tid + 128]  + ssq[tid + 192];
            atomicAdd(&stats[tid], s);
            atomicAdd(&stats[64 + tid], q);
        }
    } else {
        int* h = shm;
        for (int t = tid; t < nbuk; t += 256) h[t] = 0;
        __syncthreads();
        const int base = ((int)blockIdx.x - SB) * 4096;
#pragma unroll
        for (int i = 0; i < 16; ++i) {
            int e = base + i * 256 + tid;
            if (e < E) atomicAdd(&h[rows[e] >> BSHIFT], 1);
        }
        __syncthreads();
        for (int t = tid; t < nbuk; t += 256)
            if (h[t]) atomicAdd(&ccnt[t], h[t]);
    }
}

// ---------------------------------------------------------------------------
// K2 (fused, 9 blocks): block 0 = exclusive scan of bucket counts (cbase +
// cursor ccur + sentinel); blocks 1..8 = BN scale/shift finalize + W packing
// into bf16 MFMA B-fragments.
// ---------------------------------------------------------------------------
__global__ __launch_bounds__(256) void k2_scan_wprep(
    const int* __restrict__ ccnt, int* __restrict__ cbase,
    int* __restrict__ ccur, int nbuk,
    const float* __restrict__ stats, const float* __restrict__ gamma,
    const float* __restrict__ beta, const float* __restrict__ W,
    float* __restrict__ scsh, short* __restrict__ Wp, int N)
{
    __shared__ int s[256];
    const int tid = threadIdx.x;
    if (blockIdx.x == 0) {
        int v[4]; int tsum = 0;
#pragma unroll
        for (int j = 0; j < 4; ++j) {
            int idx = tid * 4 + j;
            v[j] = (idx < nbuk) ? ccnt[idx] : 0;
            tsum += v[j];
        }
        s[tid] = tsum;
        __syncthreads();
        for (int off = 1; off < 256; off <<= 1) {
            int t = (tid >= off) ? s[tid - off] : 0;
            __syncthreads();
            s[tid] += t;
            __syncthreads();
        }
        int run = s[tid] - tsum;
#pragma unroll
        for (int j = 0; j < 4; ++j) {
            int idx = tid * 4 + j;
            if (idx < nbuk) { cbase[idx] = run; ccur[idx] = run; }
            run += v[j];
        }
        if (tid == 255) cbase[nbuk] = s[255];
    } else {
        const int bid = blockIdx.x - 1;        // 0..7
        if (bid == 0 && tid < 64) {
            const float invN  = 1.0f / (float)N;
            const float mean  = stats[tid] * invN;
            const float var   = stats[64 + tid] * invN - mean * mean;
            const float scale = rsqrtf(var + 1e-5f) * gamma[tid];
            scsh[tid]      = scale;
            scsh[64 + tid] = beta[tid] - mean * scale;
        }
        const int sl   = bid * 256 + tid;      // slot 0..2047
        const int lane = sl & 63;
        const int pair = sl >> 6;
        const int kb   = pair & 1;
        const int ct   = pair >> 1;
        const int kbase = kb * 32 + (lane >> 4) * 8;
        const int col   = ct * 16 + (lane & 15);
        short8v v8;
#pragma unroll
        for (int j = 0; j < 8; ++j)
            v8[j] = (short)f2bf(W[(size_t)(kbase + j) * KF + col]);
        *(short8v*)(Wp + (size_t)sl * 8) = v8;
    }
}

// ---------------------------------------------------------------------------
// K3 (fused): blocks [0,EB) = binning pass (BPB=1024 edges/block, single
// LDS-atomic pass: pos reserved during first sweep, cached in registers);
// blocks [EB,EB+GB) = MFMA BN->ELU->Linear (xlin bf16, linear layout
// xlin[slot*64+f], slot=n2*4+k).  Binpass first: it's the long pole.
// ---------------------------------------------------------------------------
__global__ __launch_bounds__(256) void k3_gemm_binpass(
    const float* __restrict__ a, const float* __restrict__ scsh,
    const short* __restrict__ Wp, const float* __restrict__ b,
    unsigned short* __restrict__ xlinb, int N, int EB,
    const float* __restrict__ vals, const int* __restrict__ rows,
    const int* __restrict__ cols, int* __restrict__ ccur,
    int2* __restrict__ cv2, int E, int nbuk)
{
    __shared__ int lmem[2 * MAXBUK];     // binpass: lhist + lbase (8 KB)
    const int tid = threadIdx.x;
    if ((int)blockIdx.x < EB) {
        // ---------------- binpass body (single-atomic-pass) ----------------
        int* lhist = lmem;
        int* lbase = lmem + MAXBUK;
        for (int t = tid; t < nbuk; t += 256) lhist[t] = 0;
        __syncthreads();

        const int base = (int)blockIdx.x * BPB;
        int pk[4];   // packed edge word
        int pp[4];   // pos | (bkt<<16), or -1
#pragma unroll
        for (int i = 0; i < 4; ++i) {
            const int e = base + i * 256 + tid;
            if (e < E) {
                const int r   = rows[e];
                const int bkt = r >> BSHIFT;
                const int pos = atomicAdd(&lhist[bkt], 1);
                const int c   = cols[e];
                int k = 0, n2 = c;
                while (n2 >= N) { n2 -= N; ++k; }
                pk[i] = ((r & (BROWS - 1)) << 19) | (n2 * 4 + k);
                pp[i] = pos | (bkt << 16);
            } else {
                pp[i] = -1;
            }
        }
        __syncthreads();
        for (int t = tid; t < nbuk; t += 256) {
            const int c = lhist[t];
            lbase[t] = c ? atomicAdd(&ccur[t], c) : 0;
        }
        __syncthreads();
#pragma unroll
        for (int i = 0; i < 4; ++i) {
            if (pp[i] >= 0) {
                const int bkt = pp[i] >> 16;
                const int pos = pp[i] & 0xFFFF;
                const int e   = base + i * 256 + tid;
                cv2[lbase[bkt] + pos] = make_int2(pk[i], __float_as_int(vals[e]));
            }
        }
    } else {
        // ---------------- gemm_mfma body (round-5 proven) ----------------
        const int l   = tid & 63;
        const int w   = tid >> 6;
        const int l15 = l & 15;
        const int lg  = l >> 4;
        const int i0  = ((int)blockIdx.x - EB) * 64;

        short8v bfrag[8];
#pragma unroll
        for (int p = 0; p < 8; ++p) {
            const int ct   = w * 4 + (p >> 1);
            const int pair = ct * 2 + (p & 1);
            bfrag[p] = *(const short8v*)(Wp + (size_t)(pair * 64 + l) * 8);
        }
        float bias[4];
#pragma unroll
        for (int c = 0; c < 4; ++c) bias[c] = b[(w * 4 + c) * 16 + l15];

        float sc[16], sh[16];
#pragma unroll
        for (int kb = 0; kb < 2; ++kb) {
            const int kbase = kb * 32 + lg * 8;
#pragma unroll
            for (int j = 0; j < 8; j += 4) {
                const float4 s4 = *(const float4*)(scsh + kbase + j);
                const float4 h4 = *(const float4*)(scsh + 64 + kbase + j);
                sc[kb * 8 + j + 0] = s4.x; sc[kb * 8 + j + 1] = s4.y;
                sc[kb * 8 + j + 2] = s4.z; sc[kb * 8 + j + 3] = s4.w;
                sh[kb * 8 + j + 0] = h4.x; sh[kb * 8 + j + 1] = h4.y;
                sh[kb * 8 + j + 2] = h4.z; sh[kb * 8 + j + 3] = h4.w;
            }
        }

#pragma unroll
        for (int rg = 0; rg < 4; ++rg) {
            const int arow = i0 + rg * 16 + l15;
            float v[16];
#pragma unroll
            for (int t = 0; t < 16; ++t) v[t] = 0.f;
            if (arow < N) {
                const float4* ap = (const float4*)(a + (size_t)arow * F_IN + lg * 8);
                const float4 x0 = ap[0], x1 = ap[1];
                const float4 x2 = ap[8], x3 = ap[9];
                v[0]=x0.x; v[1]=x0.y; v[2]=x0.z; v[3]=x0.w;
                v[4]=x1.x; v[5]=x1.y; v[6]=x1.z; v[7]=x1.w;
                v[8]=x2.x; v[9]=x2.y; v[10]=x2.z; v[11]=x2.w;
                v[12]=x3.x; v[13]=x3.y; v[14]=x3.z; v[15]=x3.w;
            }
            short8v afrag0, afrag1;
#pragma unroll
            for (int t = 0; t < 16; ++t) {
                float y = fmaf(v[t], sc[t], sh[t]);
                y = (y > 0.f) ? y : expm1f(y);     // ELU alpha=1
                const short bv = (short)f2bf(y);
                if (t < 8) afrag0[t] = bv; else afrag1[t - 8] = bv;
            }
#pragma unroll
            for (int c = 0; c < 4; ++c) {
                float4v acc = {bias[c], bias[c], bias[c], bias[c]};
                acc = __builtin_amdgcn_mfma_f32_16x16x32_bf16(afrag0, bfrag[c * 2 + 0], acc, 0, 0, 0);
                acc = __builtin_amdgcn_mfma_f32_16x16x32_bf16(afrag1, bfrag[c * 2 + 1], acc, 0, 0, 0);
                const int col = (w * 4 + c) * 16 + l15;
#pragma unroll
                for (int q = 0; q < 4; ++q) {
                    const int rr = i0 + rg * 16 + lg * 4 + q;
                    if (rr < N) xlinb[(size_t)rr * KF + col] = f2bf(acc[q]);
                }
            }
        }
    }
}

// ---------------------------------------------------------------------------
// Fine sort: per-bucket counting sort into CSR order + rowoff[N+1].
// ---------------------------------------------------------------------------
__global__ __launch_bounds__(256) void fsort_kernel(
    const int2* __restrict__ cv2, const int* __restrict__ cbase,
    int2* __restrict__ cv2b, int* __restrict__ rowoff, int N, int nbuk)
{
    __shared__ int hist[BROWS];
    __shared__ int sc[BROWS];
    __shared__ int cur[BROWS];
    const int tid = threadIdx.x;
    const int b   = blockIdx.x;
    const int beg = cbase[b];
    const int end = cbase[b + 1];

    if (tid < BROWS) hist[tid] = 0;
    __syncthreads();
    for (int e = beg + tid; e < end; e += 256) {
        int lr = (cv2[e].x >> 19) & (BROWS - 1);
        atomicAdd(&hist[lr], 1);
    }
    __syncthreads();
    const int v = (tid < BROWS) ? hist[tid] : 0;
    if (tid < BROWS) sc[tid] = v;
    __syncthreads();
    for (int off = 1; off < BROWS; off <<= 1) {
        int t = (tid < BROWS && tid >= off) ? sc[tid - off] : 0;
        __syncthreads();
        if (tid < BROWS) sc[tid] += t;
        __syncthreads();
    }
    if (tid < BROWS) {
        const int excl = sc[tid] - v;
        cur[tid] = excl;
        const int row = (b << BSHIFT) + tid;
        if (row < N) rowoff[row] = beg + excl;
    }
    if (b == nbuk - 1 && tid == 0) rowoff[N] = cbase[nbuk];
    __syncthreads();
    for (int e = beg + tid; e < end; e += 256) {
        int2 m  = cv2[e];
        int lr  = (m.x >> 19) & (BROWS - 1);
        int pos = beg + atomicAdd(&cur[lr], 1);
        cv2b[pos] = m;
    }
}

// ---------------------------------------------------------------------------
// Accumulate: one wave per output row, quarter-wave edge quads (round-8
// proven, at its structural floor: L2-miss path saturated ~3.6 TB/s).
// ---------------------------------------------------------------------------
__global__ __launch_bounds__(256) void raccum_kernel(
    const int2* __restrict__ cv2b, const int* __restrict__ rowoff,
    const unsigned short* __restrict__ xlinb, float* __restrict__ out, int N)
{
    const int lane = threadIdx.x & 63;
    const int r    = blockIdx.x * 4 + (threadIdx.x >> 6);
    if (r >= N) return;
    const int q  = lane >> 4;             // edge-in-quad 0..3
    const int fl = lane & 15;             // feature group: features fl*4..fl*4+3
    const int beg = rowoff[r];
    const int end = rowoff[r + 1];
    float a0 = 0.f, a1 = 0.f, a2 = 0.f, a3 = 0.f;
    int i = beg;
    for (; i + 16 <= end; i += 16) {
#pragma unroll
        for (int j = 0; j < 4; ++j) {
            const int2 m = cv2b[i + 4 * j + q];
            const unsigned slot = (unsigned)m.x & 0x7FFFFu;
            const ushort4 g = *(const ushort4*)(xlinb + ((size_t)slot << 6) + (fl << 2));
            const float v = __int_as_float(m.y);
            a0 = fmaf(v, bfbits2f(g.x), a0);
            a1 = fmaf(v, bfbits2f(g.y), a1);
            a2 = fmaf(v, bfbits2f(g.z), a2);
            a3 = fmaf(v, bfbits2f(g.w), a3);
        }
    }
    for (; i + 4 <= end; i += 4) {
        const int2 m = cv2b[i + q];
        const unsigned slot = (unsigned)m.x & 0x7FFFFu;
        const ushort4 g = *(const ushort4*)(xlinb + ((size_t)slot << 6) + (fl << 2));
        const float v = __int_as_float(m.y);
        a0 = fmaf(v, bfbits2f(g.x), a0);
        a1 = fmaf(v, bfbits2f(g.y), a1);
        a2 = fmaf(v, bfbits2f(g.z), a2);
        a3 = fmaf(v, bfbits2f(g.w), a3);
    }
    for (; i < end; ++i) {                // 1-3 trailing edges: quad group 0
        if (q == 0) {
            const int2 m = cv2b[i];
            const unsigned slot = (unsigned)m.x & 0x7FFFFu;
            const ushort4 g = *(const ushort4*)(xlinb + ((size_t)slot << 6) + (fl << 2));
            const float v = __int_as_float(m.y);
            a0 = fmaf(v, bfbits2f(g.x), a0);
            a1 = fmaf(v, bfbits2f(g.y), a1);
            a2 = fmaf(v, bfbits2f(g.z), a2);
            a3 = fmaf(v, bfbits2f(g.w), a3);
        }
    }
    a0 += __shfl_xor(a0, 16); a0 += __shfl_xor(a0, 32);
    a1 += __shfl_xor(a1, 16); a1 += __shfl_xor(a1, 32);
    a2 += __shfl_xor(a2, 16); a2 += __shfl_xor(a2, 32);
    a3 += __shfl_xor(a3, 16); a3 += __shfl_xor(a3, 32);
    if (q == 0) {
        float4 o; o.x = a0; o.y = a1; o.z = a2; o.w = a3;
        *(float4*)(out + (size_t)r * F_IN + (fl << 2)) = o;
    }
}

// ---------------------------------------------------------------------------
// Fallback path kernels (workspace too small): stats + VALU gemm + scatter.
// ---------------------------------------------------------------------------
__global__ __launch_bounds__(256) void stats_kernel(
    const float* __restrict__ a, float* __restrict__ stats, int N)
{
    __shared__ float ssum[256];
    __shared__ float ssq[256];
    const int tid = threadIdx.x;
    const int c   = tid & 63;
    int r         = blockIdx.x * 4 + (tid >> 6);
    const int rstride = gridDim.x * 4;
    float ps = 0.f, pq = 0.f;
    for (; r < N; r += rstride) {
        float v = a[(size_t)r * F_IN + c];
        ps += v;
        pq += v * v;
    }
    ssum[tid] = ps;
    ssq[tid]  = pq;
    __syncthreads();
    if (tid < 64) {
        float s = ssum[tid] + ssum[tid + 64] + ssum[tid + 128] + ssum[tid + 192];
        float q = ssq[tid]  + ssq[tid + 64]  + ssq[tid + 128]  + ssq[tid + 192];
        atomicAdd(&stats[tid], s);
        atomicAdd(&stats[64 + tid], q);
    }
}

__global__ __launch_bounds__(256) void gemm_kernel(
    const float* __restrict__ a, const float* __restrict__ stats,
    const float* __restrict__ gamma, const float* __restrict__ beta,
    const float* __restrict__ W, const float* __restrict__ b,
    __hip_bfloat16* __restrict__ xlinb, int N)
{
    __shared__ float xs[32][F_IN];
    const int tid = threadIdx.x;
    const int c   = tid & 63;

    const float invN  = 1.0f / (float)N;
    const float mean  = stats[c] * invN;
    const float var   = stats[64 + c] * invN - mean * mean;
    const float scale = rsqrtf(var + 1e-5f) * gamma[c];
    const float shift = beta[c];

    float wreg[F_IN];
#pragma unroll
    for (int k = 0; k < F_IN; ++k) wreg[k] = W[k * KF + tid];
    const float bias = b[tid];

    const int i0 = blockIdx.x * 32;

#pragma unroll
    for (int it = 0; it < 8; ++it) {
        int idx = tid + it * 256;
        int r   = idx >> 6;
        int row = i0 + r;
        float v = 0.f;
        if (row < N) {
            v = (a[(size_t)row * F_IN + c] - mean) * scale + shift;
            v = (v > 0.f) ? v : expm1f(v);
        }
        xs[r][c] = v;
    }
    __syncthreads();

    const int rmax = min(32, N - i0);
    for (int r = 0; r < rmax; ++r) {
        const float4* xsr = (const float4*)xs[r];
        float acc = bias;
#pragma unroll
        for (int k4 = 0; k4 < 16; ++k4) {
            float4 xv = xsr[k4];
            acc = fmaf(xv.x, wreg[k4 * 4 + 0], acc);
            acc = fmaf(xv.y, wreg[k4 * 4 + 1], acc);
            acc = fmaf(xv.z, wreg[k4 * 4 + 2], acc);
            acc = fmaf(xv.w, wreg[k4 * 4 + 3], acc);
        }
        xlinb[(size_t)(i0 + r) * KF + tid] = __float2bfloat16(acc);
    }
}

__global__ __launch_bounds__(256) void scatter_kernel(
    const float* __restrict__ vals, const int* __restrict__ rows,
    const int* __restrict__ cols, const unsigned short* __restrict__ xlinb,
    float* __restrict__ out, int N, int E)
{
    const int lane = threadIdx.x & 63;
    int e = blockIdx.x * 4 + (threadIdx.x >> 6);
    const int estride = gridDim.x * 4;
    for (; e < E; e += estride) {
        float v  = vals[e];
        int   r  = rows[e];
        int   cc = cols[e];
        int k = 0, n2 = cc;
        while (n2 >= N) { n2 -= N; ++k; }
        float x = bfbits2f(xlinb[(size_t)n2 * KF + k * 64 + lane]);
        atomicAdd(&out[(size_t)r * F_IN + lane], v * x);
    }
}

extern "C" void kernel_launch(void* const* d_in, const int* in_sizes, int n_in,
                              void* d_out, int out_size, void* d_ws, size_t ws_size,
                              hipStream_t stream)
{
    const float* a     = (const float*)d_in[0];
    const float* gamma = (const float*)d_in[1];
    const float* beta  = (const float*)d_in[2];
    const float* W     = (const float*)d_in[3];
    const float* b     = (const float*)d_in[4];
    const float* vals  = (const float*)d_in[5];
    const int*   rows  = (const int*)d_in[6];
    const int*   cols  = (const int*)d_in[7];
    float*       out   = (float*)d_out;

    const int N    = in_sizes[0] / F_IN;
    const int E    = in_sizes[5];
    const int nbuk = (N + BROWS - 1) >> BSHIFT;
    const int CHB  = (E + 4095) / 4096;       // chist blocks (K1)
    const int EB   = (E + BPB - 1) / BPB;     // binpass blocks (K3)
    const int GB   = (N + 63) / 64;           // gemm blocks (K3)

    // Workspace layout:
    //   [0, 1024)        stats (128 f32)
    //   [1024, +4352)    ccnt
    //   [.., +4352)      cbase (nbuk+1)
    //   [.., +4352)      ccur
    //   [.., +512)       scsh (scale[64], shift[64])
    //   [.., +32768)     Wp (bf16 B-fragments)
    //   [.., +4(N+1))    rowoff
    //   [.., +8E)        cv2   (64B-aligned)
    //   [.., +8E)        cv2b
    //   [.., +2*N*KF)    xlin  (bf16, 256B-aligned, linear layout slot*64+f)
    char*  base     = (char*)d_ws;
    size_t o_ccnt   = 1024;
    size_t o_cbase  = o_ccnt + 4352;
    size_t o_ccur   = o_cbase + 4352;
    size_t o_scsh   = o_ccur + 4352;
    size_t o_wp     = o_scsh + 512;
    size_t o_rowoff = o_wp + 32768;
    size_t o_cv2    = (o_rowoff + (size_t)(N + 1) * 4 + 63) & ~(size_t)63;
    size_t o_cv2b   = o_cv2 + (size_t)E * 8;
    size_t o_xlin   = (o_cv2b + (size_t)E * 8 + 255) & ~(size_t)255;
    size_t need     = o_xlin + (size_t)N * KF * 2;

    const bool use_csr = (ws_size >= need) && (nbuk <= MAXBUK) && (N < (1 << 17))
                         && (BPB <= 65536);

    float* stats = (float*)base;

    if (use_csr) {
        int*            ccnt   = (int*)(base + o_ccnt);
        int*            cbase  = (int*)(base + o_cbase);
        int*            ccur   = (int*)(base + o_ccur);
        float*          scsh   = (float*)(base + o_scsh);
        short*          Wp     = (short*)(base + o_wp);
        int*            rowoff = (int*)(base + o_rowoff);
        int2*           cv2    = (int2*)(base + o_cv2);
        int2*           cv2b   = (int2*)(base + o_cv2b);
        unsigned short* xlinb  = (unsigned short*)(base + o_xlin);

        hipMemsetAsync(d_ws, 0, o_cbase, stream);   // stats + ccnt

        k1_stats_chist<<<SB + CHB, 256, 0, stream>>>(a, stats, N, rows, ccnt, E, nbuk);
        k2_scan_wprep<<<9, 256, 0, stream>>>(ccnt, cbase, ccur, nbuk,
                                             stats, gamma, beta, W, scsh, Wp, N);
        k3_gemm_binpass<<<EB + GB, 256, 0, stream>>>(a, scsh, Wp, b, xlinb, N, EB,
                                                     vals, rows, cols, ccur, cv2, E, nbuk);
        fsort_kernel<<<nbuk, 256, 0, stream>>>(cv2, cbase, cv2b, rowoff, N, nbuk);
        raccum_kernel<<<(N + 3) / 4, 256, 0, stream>>>(cv2b, rowoff, xlinb, out, N);
    } else {
        __hip_bfloat16* xlinb = (__hip_bfloat16*)(base + 1024);
        hipMemsetAsync(d_ws, 0, 512, stream);
        hipMemsetAsync(d_out, 0, (size_t)out_size * sizeof(float), stream);
        stats_kernel<<<512, 256, 0, stream>>>(a, stats, N);
        gemm_kernel<<<(N + 31) / 32, 256, 0, stream>>>(a, stats, gamma, beta, W, b, xlinb, N);
        scatter_kernel<<<8192, 256, 0, stream>>>(vals, rows, cols,
                                                 (const unsigned short*)xlinb, out, N, E);
    }
}

// Round 11
// 178.947 us; speedup vs baseline: 1.1401x; 1.1401x over previous
//
#include <hip/hip_runtime.h>
#include <hip/hip_bf16.h>

#define F_IN   64
#define KF     256    // K * F_OUT
#define BSHIFT 7      // bucket = row >> 7  (128 rows per bucket)
#define BROWS  128
#define MAXBUK 1024   // supports N up to 131072
#define SB     512    // stats blocks inside K1
#define BPB    8192   // edges per binpass block (32 per thread)

typedef __attribute__((ext_vector_type(8))) short short8v;
typedef __attribute__((ext_vector_type(4))) float float4v;

__device__ __forceinline__ float bfbits2f(unsigned short u) {
    union { unsigned i; float f; } x; x.i = ((unsigned)u) << 16; return x.f;
}
__device__ __forceinline__ unsigned short f2bf(float f) {   // RNE
    unsigned u = __float_as_uint(f);
    return (unsigned short)((u + 0x7FFF + ((u >> 16) & 1)) >> 16);
}

// ---------------------------------------------------------------------------
// K1 (fused): blocks [0,SB) = BatchNorm stats; blocks [SB,SB+CHB) = coarse
// histogram of edges per 128-row bucket.  Independent inputs -> max() time.
// ---------------------------------------------------------------------------
__global__ __launch_bounds__(256) void k1_stats_chist(
    const float* __restrict__ a, float* __restrict__ stats, int N,
    const int* __restrict__ rows, int* __restrict__ ccnt, int E, int nbuk)
{
    __shared__ int shm[MAXBUK];          // stats: 512 floats; chist: nbuk ints
    const int tid = threadIdx.x;
    if ((int)blockIdx.x < SB) {
        float* ssum = (float*)shm;
        float* ssq  = ((float*)shm) + 256;
        const int c = tid & 63;
        int r = blockIdx.x * 4 + (tid >> 6);
        const int rstride = SB * 4;
        float ps = 0.f, pq = 0.f;
        for (; r < N; r += rstride) {
            float v = a[(size_t)r * F_IN + c];
            ps += v;
            pq += v * v;
        }
        ssum[tid] = ps;
        ssq[tid]  = pq;
        __syncthreads();
        if (tid < 64) {
            float s = ssum[tid] + ssum[tid + 64] + ssum[tid + 128] + ssum[tid + 192];
            float q = ssq[tid]  + ssq[tid + 64]  + ssq[tid + 128]  + ssq[tid + 192];
            atomicAdd(&stats[tid], s);
            atomicAdd(&stats[64 + tid], q);
        }
    } else {
        int* h = shm;
        for (int t = tid; t < nbuk; t += 256) h[t] = 0;
        __syncthreads();
        const int base = ((int)blockIdx.x - SB) * 4096;
#pragma unroll
        for (int i = 0; i < 16; ++i) {
            int e = base + i * 256 + tid;
            if (e < E) atomicAdd(&h[rows[e] >> BSHIFT], 1);
        }
        __syncthreads();
        for (int t = tid; t < nbuk; t += 256)
            if (h[t]) atomicAdd(&ccnt[t], h[t]);
    }
}

// ---------------------------------------------------------------------------
// K2 (fused, 9 blocks): block 0 = exclusive scan of bucket counts (cbase +
// cursor ccur + sentinel); blocks 1..8 = BN scale/shift finalize + W packing
// into bf16 MFMA B-fragments.
// ---------------------------------------------------------------------------
__global__ __launch_bounds__(256) void k2_scan_wprep(
    const int* __restrict__ ccnt, int* __restrict__ cbase,
    int* __restrict__ ccur, int nbuk,
    const float* __restrict__ stats, const float* __restrict__ gamma,
    const float* __restrict__ beta, const float* __restrict__ W,
    float* __restrict__ scsh, short* __restrict__ Wp, int N)
{
    __shared__ int s[256];
    const int tid = threadIdx.x;
    if (blockIdx.x == 0) {
        int v[4]; int tsum = 0;
#pragma unroll
        for (int j = 0; j < 4; ++j) {
            int idx = tid * 4 + j;
            v[j] = (idx < nbuk) ? ccnt[idx] : 0;
            tsum += v[j];
        }
        s[tid] = tsum;
        __syncthreads();
        for (int off = 1; off < 256; off <<= 1) {
            int t = (tid >= off) ? s[tid - off] : 0;
            __syncthreads();
            s[tid] += t;
            __syncthreads();
        }
        int run = s[tid] - tsum;
#pragma unroll
        for (int j = 0; j < 4; ++j) {
            int idx = tid * 4 + j;
            if (idx < nbuk) { cbase[idx] = run; ccur[idx] = run; }
            run += v[j];
        }
        if (tid == 255) cbase[nbuk] = s[255];
    } else {
        const int bid = blockIdx.x - 1;        // 0..7
        if (bid == 0 && tid < 64) {
            const float invN  = 1.0f / (float)N;
            const float mean  = stats[tid] * invN;
            const float var   = stats[64 + tid] * invN - mean * mean;
            const float scale = rsqrtf(var + 1e-5f) * gamma[tid];
            scsh[tid]      = scale;
            scsh[64 + tid] = beta[tid] - mean * scale;
        }
        const int sl   = bid * 256 + tid;      // slot 0..2047
        const int lane = sl & 63;
        const int pair = sl >> 6;
        const int kb   = pair & 1;
        const int ct   = pair >> 1;
        const int kbase = kb * 32 + (lane >> 4) * 8;
        const int col   = ct * 16 + (lane & 15);
        short8v v8;
#pragma unroll
        for (int j = 0; j < 8; ++j)
            v8[j] = (short)f2bf(W[(size_t)(kbase + j) * KF + col]);
        *(short8v*)(Wp + (size_t)sl * 8) = v8;
    }
}

// ---------------------------------------------------------------------------
// K3 (fused): blocks [0,GB) = MFMA BN->ELU->Linear (round-5 proven, byte-
// identical); blocks [GB,GB+EB) = binning pass, BPB=8192 edges/block,
// SINGLE LDS-atomic pass: pos reserved while counting, packed {bkt,lr,pos}
// kept in 32 VGPRs; cols/vals first read in the write sweep.  8192/782 ~
// 10.5 edges (84B) per (block,bucket) chunk -> cv2 lines mostly fully
// written by one block (write-density fix; round-10's BPB=1024 broke this).
// ---------------------------------------------------------------------------
__global__ __launch_bounds__(256) void k3_gemm_binpass(
    const float* __restrict__ a, const float* __restrict__ scsh,
    const short* __restrict__ Wp, const float* __restrict__ b,
    unsigned short* __restrict__ xlinb, int N, int GB,
    const float* __restrict__ vals, const int* __restrict__ rows,
    const int* __restrict__ cols, int* __restrict__ ccur,
    int2* __restrict__ cv2, int E, int nbuk)
{
    __shared__ int lmem[2 * MAXBUK];     // binpass: lhist + lbase (8 KB)
    const int tid = threadIdx.x;
    if ((int)blockIdx.x < GB) {
        // ---------------- gemm_mfma body (round-5 proven) ----------------
        const int l   = tid & 63;
        const int w   = tid >> 6;
        const int l15 = l & 15;
        const int lg  = l >> 4;
        const int i0  = blockIdx.x * 64;

        short8v bfrag[8];
#pragma unroll
        for (int p = 0; p < 8; ++p) {
            const int ct   = w * 4 + (p >> 1);
            const int pair = ct * 2 + (p & 1);
            bfrag[p] = *(const short8v*)(Wp + (size_t)(pair * 64 + l) * 8);
        }
        float bias[4];
#pragma unroll
        for (int c = 0; c < 4; ++c) bias[c] = b[(w * 4 + c) * 16 + l15];

        float sc[16], sh[16];
#pragma unroll
        for (int kb = 0; kb < 2; ++kb) {
            const int kbase = kb * 32 + lg * 8;
#pragma unroll
            for (int j = 0; j < 8; j += 4) {
                const float4 s4 = *(const float4*)(scsh + kbase + j);
                const float4 h4 = *(const float4*)(scsh + 64 + kbase + j);
                sc[kb * 8 + j + 0] = s4.x; sc[kb * 8 + j + 1] = s4.y;
                sc[kb * 8 + j + 2] = s4.z; sc[kb * 8 + j + 3] = s4.w;
                sh[kb * 8 + j + 0] = h4.x; sh[kb * 8 + j + 1] = h4.y;
                sh[kb * 8 + j + 2] = h4.z; sh[kb * 8 + j + 3] = h4.w;
            }
        }

#pragma unroll
        for (int rg = 0; rg < 4; ++rg) {
            const int arow = i0 + rg * 16 + l15;
            float v[16];
#pragma unroll
            for (int t = 0; t < 16; ++t) v[t] = 0.f;
            if (arow < N) {
                const float4* ap = (const float4*)(a + (size_t)arow * F_IN + lg * 8);
                const float4 x0 = ap[0], x1 = ap[1];
                const float4 x2 = ap[8], x3 = ap[9];
                v[0]=x0.x; v[1]=x0.y; v[2]=x0.z; v[3]=x0.w;
                v[4]=x1.x; v[5]=x1.y; v[6]=x1.z; v[7]=x1.w;
                v[8]=x2.x; v[9]=x2.y; v[10]=x2.z; v[11]=x2.w;
                v[12]=x3.x; v[13]=x3.y; v[14]=x3.z; v[15]=x3.w;
            }
            short8v afrag0, afrag1;
#pragma unroll
            for (int t = 0; t < 16; ++t) {
                float y = fmaf(v[t], sc[t], sh[t]);
                y = (y > 0.f) ? y : expm1f(y);     // ELU alpha=1
                const short bv = (short)f2bf(y);
                if (t < 8) afrag0[t] = bv; else afrag1[t - 8] = bv;
            }
#pragma unroll
            for (int c = 0; c < 4; ++c) {
                float4v acc = {bias[c], bias[c], bias[c], bias[c]};
                acc = __builtin_amdgcn_mfma_f32_16x16x32_bf16(afrag0, bfrag[c * 2 + 0], acc, 0, 0, 0);
                acc = __builtin_amdgcn_mfma_f32_16x16x32_bf16(afrag1, bfrag[c * 2 + 1], acc, 0, 0, 0);
                const int col = (w * 4 + c) * 16 + l15;
#pragma unroll
                for (int q = 0; q < 4; ++q) {
                    const int rr = i0 + rg * 16 + lg * 4 + q;
                    if (rr < N) xlinb[(size_t)rr * KF + col] = f2bf(acc[q]);
                }
            }
        }
    } else {
        // -------- binpass body: single-pass, BPB=8192, reg-cached pos --------
        int* lhist = lmem;
        int* lbase = lmem + MAXBUK;
        for (int t = tid; t < nbuk; t += 256) lhist[t] = 0;
        __syncthreads();

        const int base = ((int)blockIdx.x - GB) * BPB;
        // pp[i] = pos | (lr<<13) | (bkt<<20);  -1 if out of range
        int pp[32];
#pragma unroll
        for (int i = 0; i < 32; ++i) {
            const int e = base + i * 256 + tid;
            if (e < E) {
                const int r   = rows[e];
                const int bkt = r >> BSHIFT;
                const int pos = atomicAdd(&lhist[bkt], 1);
                pp[i] = pos | ((r & (BROWS - 1)) << 13) | (bkt << 20);
            } else {
                pp[i] = -1;
            }
        }
        __syncthreads();
        for (int t = tid; t < nbuk; t += 256) {
            const int c = lhist[t];
            lbase[t] = c ? atomicAdd(&ccur[t], c) : 0;
        }
        __syncthreads();
#pragma unroll
        for (int i = 0; i < 32; ++i) {
            if (pp[i] >= 0) {
                const int e   = base + i * 256 + tid;
                const int pos = pp[i] & 0x1FFF;
                const int lr  = (pp[i] >> 13) & 0x7F;
                const int bkt = pp[i] >> 20;
                const int c   = cols[e];
                int k = 0, n2 = c;
                while (n2 >= N) { n2 -= N; ++k; }
                const int packed = (lr << 19) | (n2 * 4 + k);
                cv2[lbase[bkt] + pos] = make_int2(packed, __float_as_int(vals[e]));
            }
        }
    }
}

// ---------------------------------------------------------------------------
// Fine sort: per-bucket counting sort into CSR order + rowoff[N+1].
// ---------------------------------------------------------------------------
__global__ __launch_bounds__(256) void fsort_kernel(
    const int2* __restrict__ cv2, const int* __restrict__ cbase,
    int2* __restrict__ cv2b, int* __restrict__ rowoff, int N, int nbuk)
{
    __shared__ int hist[BROWS];
    __shared__ int sc[BROWS];
    __shared__ int cur[BROWS];
    const int tid = threadIdx.x;
    const int b   = blockIdx.x;
    const int beg = cbase[b];
    const int end = cbase[b + 1];

    if (tid < BROWS) hist[tid] = 0;
    __syncthreads();
    for (int e = beg + tid; e < end; e += 256) {
        int lr = (cv2[e].x >> 19) & (BROWS - 1);
        atomicAdd(&hist[lr], 1);
    }
    __syncthreads();
    const int v = (tid < BROWS) ? hist[tid] : 0;
    if (tid < BROWS) sc[tid] = v;
    __syncthreads();
    for (int off = 1; off < BROWS; off <<= 1) {
        int t = (tid < BROWS && tid >= off) ? sc[tid - off] : 0;
        __syncthreads();
        if (tid < BROWS) sc[tid] += t;
        __syncthreads();
    }
    if (tid < BROWS) {
        const int excl = sc[tid] - v;
        cur[tid] = excl;
        const int row = (b << BSHIFT) + tid;
        if (row < N) rowoff[row] = beg + excl;
    }
    if (b == nbuk - 1 && tid == 0) rowoff[N] = cbase[nbuk];
    __syncthreads();
    for (int e = beg + tid; e < end; e += 256) {
        int2 m  = cv2[e];
        int lr  = (m.x >> 19) & (BROWS - 1);
        int pos = beg + atomicAdd(&cur[lr], 1);
        cv2b[pos] = m;
    }
}

// ---------------------------------------------------------------------------
// Accumulate: one wave per output row, quarter-wave edge quads (round-8
// proven, at its structural floor: L2-miss path saturated ~3.6 TB/s).
// ---------------------------------------------------------------------------
__global__ __launch_bounds__(256) void raccum_kernel(
    const int2* __restrict__ cv2b, const int* __restrict__ rowoff,
    const unsigned short* __restrict__ xlinb, float* __restrict__ out, int N)
{
    const int lane = threadIdx.x & 63;
    const int r    = blockIdx.x * 4 + (threadIdx.x >> 6);
    if (r >= N) return;
    const int q  = lane >> 4;             // edge-in-quad 0..3
    const int fl = lane & 15;             // feature group: features fl*4..fl*4+3
    const int beg = rowoff[r];
    const int end = rowoff[r + 1];
    float a0 = 0.f, a1 = 0.f, a2 = 0.f, a3 = 0.f;
    int i = beg;
    for (; i + 16 <= end; i += 16) {
#pragma unroll
        for (int j = 0; j < 4; ++j) {
            const int2 m = cv2b[i + 4 * j + q];
            const unsigned slot = (unsigned)m.x & 0x7FFFFu;
            const ushort4 g = *(const ushort4*)(xlinb + ((size_t)slot << 6) + (fl << 2));
            const float v = __int_as_float(m.y);
            a0 = fmaf(v, bfbits2f(g.x), a0);
            a1 = fmaf(v, bfbits2f(g.y), a1);
            a2 = fmaf(v, bfbits2f(g.z), a2);
            a3 = fmaf(v, bfbits2f(g.w), a3);
        }
    }
    for (; i + 4 <= end; i += 4) {
        const int2 m = cv2b[i + q];
        const unsigned slot = (unsigned)m.x & 0x7FFFFu;
        const ushort4 g = *(const ushort4*)(xlinb + ((size_t)slot << 6) + (fl << 2));
        const float v = __int_as_float(m.y);
        a0 = fmaf(v, bfbits2f(g.x), a0);
        a1 = fmaf(v, bfbits2f(g.y), a1);
        a2 = fmaf(v, bfbits2f(g.z), a2);
        a3 = fmaf(v, bfbits2f(g.w), a3);
    }
    for (; i < end; ++i) {                // 1-3 trailing edges: quad group 0
        if (q == 0) {
            const int2 m = cv2b[i];
            const unsigned slot = (unsigned)m.x & 0x7FFFFu;
            const ushort4 g = *(const ushort4*)(xlinb + ((size_t)slot << 6) + (fl << 2));
            const float v = __int_as_float(m.y);
            a0 = fmaf(v, bfbits2f(g.x), a0);
            a1 = fmaf(v, bfbits2f(g.y), a1);
            a2 = fmaf(v, bfbits2f(g.z), a2);
            a3 = fmaf(v, bfbits2f(g.w), a3);
        }
    }
    a0 += __shfl_xor(a0, 16); a0 += __shfl_xor(a0, 32);
    a1 += __shfl_xor(a1, 16); a1 += __shfl_xor(a1, 32);
    a2 += __shfl_xor(a2, 16); a2 += __shfl_xor(a2, 32);
    a3 += __shfl_xor(a3, 16); a3 += __shfl_xor(a3, 32);
    if (q == 0) {
        float4 o; o.x = a0; o.y = a1; o.z = a2; o.w = a3;
        *(float4*)(out + (size_t)r * F_IN + (fl << 2)) = o;
    }
}

// ---------------------------------------------------------------------------
// Fallback path kernels (workspace too small): stats + VALU gemm + scatter.
// ---------------------------------------------------------------------------
__global__ __launch_bounds__(256) void stats_kernel(
    const float* __restrict__ a, float* __restrict__ stats, int N)
{
    __shared__ float ssum[256];
    __shared__ float ssq[256];
    const int tid = threadIdx.x;
    const int c   = tid & 63;
    int r         = blockIdx.x * 4 + (tid >> 6);
    const int rstride = gridDim.x * 4;
    float ps = 0.f, pq = 0.f;
    for (; r < N; r += rstride) {
        float v = a[(size_t)r * F_IN + c];
        ps += v;
        pq += v * v;
    }
    ssum[tid] = ps;
    ssq[tid]  = pq;
    __syncthreads();
    if (tid < 64) {
        float s = ssum[tid] + ssum[tid + 64] + ssum[tid + 128] + ssum[tid + 192];
        float q = ssq[tid]  + ssq[tid + 64]  + ssq[tid + 128]  + ssq[tid + 192];
        atomicAdd(&stats[tid], s);
        atomicAdd(&stats[64 + tid], q);
    }
}

__global__ __launch_bounds__(256) void gemm_kernel(
    const float* __restrict__ a, const float* __restrict__ stats,
    const float* __restrict__ gamma, const float* __restrict__ beta,
    const float* __restrict__ W, const float* __restrict__ b,
    __hip_bfloat16* __restrict__ xlinb, int N)
{
    __shared__ float xs[32][F_IN];
    const int tid = threadIdx.x;
    const int c   = tid & 63;

    const float invN  = 1.0f / (float)N;
    const float mean  = stats[c] * invN;
    const float var   = stats[64 + c] * invN - mean * mean;
    const float scale = rsqrtf(var + 1e-5f) * gamma[c];
    const float shift = beta[c];

    float wreg[F_IN];
#pragma unroll
    for (int k = 0; k < F_IN; ++k) wreg[k] = W[k * KF + tid];
    const float bias = b[tid];

    const int i0 = blockIdx.x * 32;

#pragma unroll
    for (int it = 0; it < 8; ++it) {
        int idx = tid + it * 256;
        int r   = idx >> 6;
        int row = i0 + r;
        float v = 0.f;
        if (row < N) {
            v = (a[(size_t)row * F_IN + c] - mean) * scale + shift;
            v = (v > 0.f) ? v : expm1f(v);
        }
        xs[r][c] = v;
    }
    __syncthreads();

    const int rmax = min(32, N - i0);
    for (int r = 0; r < rmax; ++r) {
        const float4* xsr = (const float4*)xs[r];
        float acc = bias;
#pragma unroll
        for (int k4 = 0; k4 < 16; ++k4) {
            float4 xv = xsr[k4];
            acc = fmaf(xv.x, wreg[k4 * 4 + 0], acc);
            acc = fmaf(xv.y, wreg[k4 * 4 + 1], acc);
            acc = fmaf(xv.z, wreg[k4 * 4 + 2], acc);
            acc = fmaf(xv.w, wreg[k4 * 4 + 3], acc);
        }
        xlinb[(size_t)(i0 + r) * KF + tid] = __float2bfloat16(acc);
    }
}

__global__ __launch_bounds__(256) void scatter_kernel(
    const float* __restrict__ vals, const int* __restrict__ rows,
    const int* __restrict__ cols, const unsigned short* __restrict__ xlinb,
    float* __restrict__ out, int N, int E)
{
    const int lane = threadIdx.x & 63;
    int e = blockIdx.x * 4 + (threadIdx.x >> 6);
    const int estride = gridDim.x * 4;
    for (; e < E; e += estride) {
        float v  = vals[e];
        int   r  = rows[e];
        int   cc = cols[e];
        int k = 0, n2 = cc;
        while (n2 >= N) { n2 -= N; ++k; }
        float x = bfbits2f(xlinb[(size_t)n2 * KF + k * 64 + lane]);
        atomicAdd(&out[(size_t)r * F_IN + lane], v * x);
    }
}

extern "C" void kernel_launch(void* const* d_in, const int* in_sizes, int n_in,
                              void* d_out, int out_size, void* d_ws, size_t ws_size,
                              hipStream_t stream)
{
    const float* a     = (const float*)d_in[0];
    const float* gamma = (const float*)d_in[1];
    const float* beta  = (const float*)d_in[2];
    const float* W     = (const float*)d_in[3];
    const float* b     = (const float*)d_in[4];
    const float* vals  = (const float*)d_in[5];
    const int*   rows  = (const int*)d_in[6];
    const int*   cols  = (const int*)d_in[7];
    float*       out   = (float*)d_out;

    const int N    = in_sizes[0] / F_IN;
    const int E    = in_sizes[5];
    const int nbuk = (N + BROWS - 1) >> BSHIFT;
    const int CHB  = (E + 4095) / 4096;       // chist blocks (K1)
    const int EB   = (E + BPB - 1) / BPB;     // binpass blocks (K3)
    const int GB   = (N + 63) / 64;           // gemm blocks (K3)

    // Workspace layout:
    //   [0, 1024)        stats (128 f32)
    //   [1024, +4352)    ccnt
    //   [.., +4352)      cbase (nbuk+1)
    //   [.., +4352)      ccur
    //   [.., +512)       scsh (scale[64], shift[64])
    //   [.., +32768)     Wp (bf16 B-fragments)
    //   [.., +4(N+1))    rowoff
    //   [.., +8E)        cv2   (64B-aligned)
    //   [.., +8E)        cv2b
    //   [.., +2*N*KF)    xlin  (bf16, 256B-aligned, linear layout slot*64+f)
    char*  base     = (char*)d_ws;
    size_t o_ccnt   = 1024;
    size_t o_cbase  = o_ccnt + 4352;
    size_t o_ccur   = o_cbase + 4352;
    size_t o_scsh   = o_ccur + 4352;
    size_t o_wp     = o_scsh + 512;
    size_t o_rowoff = o_wp + 32768;
    size_t o_cv2    = (o_rowoff + (size_t)(N + 1) * 4 + 63) & ~(size_t)63;
    size_t o_cv2b   = o_cv2 + (size_t)E * 8;
    size_t o_xlin   = (o_cv2b + (size_t)E * 8 + 255) & ~(size_t)255;
    size_t need     = o_xlin + (size_t)N * KF * 2;

    const bool use_csr = (ws_size >= need) && (nbuk <= MAXBUK) && (N < (1 << 17));

    float* stats = (float*)base;

    if (use_csr) {
        int*            ccnt   = (int*)(base + o_ccnt);
        int*            cbase  = (int*)(base + o_cbase);
        int*            ccur   = (int*)(base + o_ccur);
        float*          scsh   = (float*)(base + o_scsh);
        short*          Wp     = (short*)(base + o_wp);
        int*            rowoff = (int*)(base + o_rowoff);
        int2*           cv2    = (int2*)(base + o_cv2);
        int2*           cv2b   = (int2*)(base + o_cv2b);
        unsigned short* xlinb  = (unsigned short*)(base + o_xlin);

        hipMemsetAsync(d_ws, 0, o_cbase, stream);   // stats + ccnt

        k1_stats_chist<<<SB + CHB, 256, 0, stream>>>(a, stats, N, rows, ccnt, E, nbuk);
        k2_scan_wprep<<<9, 256, 0, stream>>>(ccnt, cbase, ccur, nbuk,
                                             stats, gamma, beta, W, scsh, Wp, N);
        k3_gemm_binpass<<<GB + EB, 256, 0, stream>>>(a, scsh, Wp, b, xlinb, N, GB,
                                                     vals, rows, cols, ccur, cv2, E, nbuk);
        fsort_kernel<<<nbuk, 256, 0, stream>>>(cv2, cbase, cv2b, rowoff, N, nbuk);
        raccum_kernel<<<(N + 3) / 4, 256, 0, stream>>>(cv2b, rowoff, xlinb, out, N);
    } else {
        __hip_bfloat16* xlinb = (__hip_bfloat16*)(base + 1024);
        hipMemsetAsync(d_ws, 0, 512, stream);
        hipMemsetAsync(d_out, 0, (size_t)out_size * sizeof(float), stream);
        stats_kernel<<<512, 256, 0, stream>>>(a, stats, N);
        gemm_kernel<<<(N + 31) / 32, 256, 0, stream>>>(a, stats, gamma, beta, W, b, xlinb, N);
        scatter_kernel<<<8192, 256, 0, stream>>>(vals, rows, cols,
                                                 (const unsigned short*)xlinb, out, N, E);
    }
}

// Round 12
// 169.171 us; speedup vs baseline: 1.2060x; 1.0578x over previous
//
#include <hip/hip_runtime.h>
#include <hip/hip_bf16.h>

#define F_IN   64
#define KF     256    // K * F_OUT
#define BSHIFT 7      // bucket = row >> 7  (128 rows per bucket)
#define BROWS  128
#define MAXBUK 1024   // supports N up to 131072
#define SB     512    // stats blocks inside K1
#define BPB    4096   // edges per binpass block (16 per thread)

typedef __attribute__((ext_vector_type(8))) short short8v;
typedef __attribute__((ext_vector_type(4))) float float4v;

__device__ __forceinline__ float bfbits2f(unsigned short u) {
    union { unsigned i; float f; } x; x.i = ((unsigned)u) << 16; return x.f;
}
__device__ __forceinline__ unsigned short f2bf(float f) {   // RNE
    unsigned u = __float_as_uint(f);
    return (unsigned short)((u + 0x7FFF + ((u >> 16) & 1)) >> 16);
}

// ---------------------------------------------------------------------------
// K1 (fused): blocks [0,SB) = BatchNorm stats; blocks [SB,SB+CHB) = coarse
// histogram of edges per 128-row bucket.
// ---------------------------------------------------------------------------
__global__ __launch_bounds__(256) void k1_stats_chist(
    const float* __restrict__ a, float* __restrict__ stats, int N,
    const int* __restrict__ rows, int* __restrict__ ccnt, int E, int nbuk)
{
    __shared__ int shm[MAXBUK];          // stats: 512 floats; chist: nbuk ints
    const int tid = threadIdx.x;
    if ((int)blockIdx.x < SB) {
        float* ssum = (float*)shm;
        float* ssq  = ((float*)shm) + 256;
        const int c = tid & 63;
        int r = blockIdx.x * 4 + (tid >> 6);
        const int rstride = SB * 4;
        float ps = 0.f, pq = 0.f;
        for (; r < N; r += rstride) {
            float v = a[(size_t)r * F_IN + c];
            ps += v;
            pq += v * v;
        }
        ssum[tid] = ps;
        ssq[tid]  = pq;
        __syncthreads();
        if (tid < 64) {
            float s = ssum[tid] + ssum[tid + 64] + ssum[tid + 128] + ssum[tid + 192];
            float q = ssq[tid]  + ssq[tid + 64]  + ssq[tid + 128]  + ssq[tid + 192];
            atomicAdd(&stats[tid], s);
            atomicAdd(&stats[64 + tid], q);
        }
    } else {
        int* h = shm;
        for (int t = tid; t < nbuk; t += 256) h[t] = 0;
        __syncthreads();
        const int base = ((int)blockIdx.x - SB) * 4096;
#pragma unroll
        for (int i = 0; i < 16; ++i) {
            int e = base + i * 256 + tid;
            if (e < E) atomicAdd(&h[rows[e] >> BSHIFT], 1);
        }
        __syncthreads();
        for (int t = tid; t < nbuk; t += 256)
            if (h[t]) atomicAdd(&ccnt[t], h[t]);
    }
}

// ---------------------------------------------------------------------------
// K2 (fused, 9 blocks): block 0 = exclusive scan of bucket counts (cbase +
// cursor ccur + sentinel); blocks 1..8 = BN scale/shift finalize + W packing.
// ---------------------------------------------------------------------------
__global__ __launch_bounds__(256) void k2_scan_wprep(
    const int* __restrict__ ccnt, int* __restrict__ cbase,
    int* __restrict__ ccur, int nbuk,
    const float* __restrict__ stats, const float* __restrict__ gamma,
    const float* __restrict__ beta, const float* __restrict__ W,
    float* __restrict__ scsh, short* __restrict__ Wp, int N)
{
    __shared__ int s[256];
    const int tid = threadIdx.x;
    if (blockIdx.x == 0) {
        int v[4]; int tsum = 0;
#pragma unroll
        for (int j = 0; j < 4; ++j) {
            int idx = tid * 4 + j;
            v[j] = (idx < nbuk) ? ccnt[idx] : 0;
            tsum += v[j];
        }
        s[tid] = tsum;
        __syncthreads();
        for (int off = 1; off < 256; off <<= 1) {
            int t = (tid >= off) ? s[tid - off] : 0;
            __syncthreads();
            s[tid] += t;
            __syncthreads();
        }
        int run = s[tid] - tsum;
#pragma unroll
        for (int j = 0; j < 4; ++j) {
            int idx = tid * 4 + j;
            if (idx < nbuk) { cbase[idx] = run; ccur[idx] = run; }
            run += v[j];
        }
        if (tid == 255) cbase[nbuk] = s[255];
    } else {
        const int bid = blockIdx.x - 1;        // 0..7
        if (bid == 0 && tid < 64) {
            const float invN  = 1.0f / (float)N;
            const float mean  = stats[tid] * invN;
            const float var   = stats[64 + tid] * invN - mean * mean;
            const float scale = rsqrtf(var + 1e-5f) * gamma[tid];
            scsh[tid]      = scale;
            scsh[64 + tid] = beta[tid] - mean * scale;
        }
        const int sl   = bid * 256 + tid;      // slot 0..2047
        const int lane = sl & 63;
        const int pair = sl >> 6;
        const int kb   = pair & 1;
        const int ct   = pair >> 1;
        const int kbase = kb * 32 + (lane >> 4) * 8;
        const int col   = ct * 16 + (lane & 15);
        short8v v8;
#pragma unroll
        for (int j = 0; j < 8; ++j)
            v8[j] = (short)f2bf(W[(size_t)(kbase + j) * KF + col]);
        *(short8v*)(Wp + (size_t)sl * 8) = v8;
    }
}

// ---------------------------------------------------------------------------
// K3 (fused): blocks [0,EB) = binning pass FIRST (long pole co-schedules
// with gemm): BPB=4096, SINGLE LDS-atomic pass (pos reserved while counting,
// packed {bkt,lr,pos} in 16 VGPRs; cols/vals first read in write sweep).
// blocks [EB,EB+GB) = MFMA BN->ELU->Linear (round-5 proven, byte-identical).
// ---------------------------------------------------------------------------
__global__ __launch_bounds__(256) void k3_gemm_binpass(
    const float* __restrict__ a, const float* __restrict__ scsh,
    const short* __restrict__ Wp, const float* __restrict__ b,
    unsigned short* __restrict__ xlinb, int N, int EB,
    const float* __restrict__ vals, const int* __restrict__ rows,
    const int* __restrict__ cols, int* __restrict__ ccur,
    int2* __restrict__ cv2, int E, int nbuk)
{
    __shared__ int lmem[2 * MAXBUK];     // binpass: lhist + lbase (8 KB)
    const int tid = threadIdx.x;
    if ((int)blockIdx.x < EB) {
        // -------- binpass body: single-pass, BPB=4096, reg-cached pos --------
        int* lhist = lmem;
        int* lbase = lmem + MAXBUK;
        for (int t = tid; t < nbuk; t += 256) lhist[t] = 0;
        __syncthreads();

        const int base = (int)blockIdx.x * BPB;
        int pp[16];   // pos | (lr<<13) | (bkt<<20); -1 if out of range
#pragma unroll
        for (int i = 0; i < 16; ++i) {
            const int e = base + i * 256 + tid;
            if (e < E) {
                const int r   = rows[e];
                const int bkt = r >> BSHIFT;
                const int pos = atomicAdd(&lhist[bkt], 1);
                pp[i] = pos | ((r & (BROWS - 1)) << 13) | (bkt << 20);
            } else {
                pp[i] = -1;
            }
        }
        __syncthreads();
        for (int t = tid; t < nbuk; t += 256) {
            const int c = lhist[t];
            lbase[t] = c ? atomicAdd(&ccur[t], c) : 0;
        }
        __syncthreads();
#pragma unroll
        for (int i = 0; i < 16; ++i) {
            if (pp[i] >= 0) {
                const int e   = base + i * 256 + tid;
                const int pos = pp[i] & 0x1FFF;
                const int lr  = (pp[i] >> 13) & 0x7F;
                const int bkt = pp[i] >> 20;
                const int c   = cols[e];
                int k = 0, n2 = c;
                while (n2 >= N) { n2 -= N; ++k; }
                cv2[lbase[bkt] + pos] =
                    make_int2((lr << 19) | (n2 * 4 + k), __float_as_int(vals[e]));
            }
        }
    } else {
        // ---------------- gemm_mfma body (round-5 proven) ----------------
        const int l   = tid & 63;
        const int w   = tid >> 6;
        const int l15 = l & 15;
        const int lg  = l >> 4;
        const int i0  = ((int)blockIdx.x - EB) * 64;

        short8v bfrag[8];
#pragma unroll
        for (int p = 0; p < 8; ++p) {
            const int ct   = w * 4 + (p >> 1);
            const int pair = ct * 2 + (p & 1);
            bfrag[p] = *(const short8v*)(Wp + (size_t)(pair * 64 + l) * 8);
        }
        float bias[4];
#pragma unroll
        for (int c = 0; c < 4; ++c) bias[c] = b[(w * 4 + c) * 16 + l15];

        float sc[16], sh[16];
#pragma unroll
        for (int kb = 0; kb < 2; ++kb) {
            const int kbase = kb * 32 + lg * 8;
#pragma unroll
            for (int j = 0; j < 8; j += 4) {
                const float4 s4 = *(const float4*)(scsh + kbase + j);
                const float4 h4 = *(const float4*)(scsh + 64 + kbase + j);
                sc[kb * 8 + j + 0] = s4.x; sc[kb * 8 + j + 1] = s4.y;
                sc[kb * 8 + j + 2] = s4.z; sc[kb * 8 + j + 3] = s4.w;
                sh[kb * 8 + j + 0] = h4.x; sh[kb * 8 + j + 1] = h4.y;
                sh[kb * 8 + j + 2] = h4.z; sh[kb * 8 + j + 3] = h4.w;
            }
        }

#pragma unroll
        for (int rg = 0; rg < 4; ++rg) {
            const int arow = i0 + rg * 16 + l15;
            float v[16];
#pragma unroll
            for (int t = 0; t < 16; ++t) v[t] = 0.f;
            if (arow < N) {
                const float4* ap = (const float4*)(a + (size_t)arow * F_IN + lg * 8);
                const float4 x0 = ap[0], x1 = ap[1];
                const float4 x2 = ap[8], x3 = ap[9];
                v[0]=x0.x; v[1]=x0.y; v[2]=x0.z; v[3]=x0.w;
                v[4]=x1.x; v[5]=x1.y; v[6]=x1.z; v[7]=x1.w;
                v[8]=x2.x; v[9]=x2.y; v[10]=x2.z; v[11]=x2.w;
                v[12]=x3.x; v[13]=x3.y; v[14]=x3.z; v[15]=x3.w;
            }
            short8v afrag0, afrag1;
#pragma unroll
            for (int t = 0; t < 16; ++t) {
                float y = fmaf(v[t], sc[t], sh[t]);
                y = (y > 0.f) ? y : expm1f(y);     // ELU alpha=1
                const short bv = (short)f2bf(y);
                if (t < 8) afrag0[t] = bv; else afrag1[t - 8] = bv;
            }
#pragma unroll
            for (int c = 0; c < 4; ++c) {
                float4v acc = {bias[c], bias[c], bias[c], bias[c]};
                acc = __builtin_amdgcn_mfma_f32_16x16x32_bf16(afrag0, bfrag[c * 2 + 0], acc, 0, 0, 0);
                acc = __builtin_amdgcn_mfma_f32_16x16x32_bf16(afrag1, bfrag[c * 2 + 1], acc, 0, 0, 0);
                const int col = (w * 4 + c) * 16 + l15;
#pragma unroll
                for (int q = 0; q < 4; ++q) {
                    const int rr = i0 + rg * 16 + lg * 4 + q;
                    if (rr < N) xlinb[(size_t)rr * KF + col] = f2bf(acc[q]);
                }
            }
        }
    }
}

// ---------------------------------------------------------------------------
// Fine sort: per-bucket counting sort into CSR order + rowoff[N+1].
// ---------------------------------------------------------------------------
__global__ __launch_bounds__(256) void fsort_kernel(
    const int2* __restrict__ cv2, const int* __restrict__ cbase,
    int2* __restrict__ cv2b, int* __restrict__ rowoff, int N, int nbuk)
{
    __shared__ int hist[BROWS];
    __shared__ int sc[BROWS];
    __shared__ int cur[BROWS];
    const int tid = threadIdx.x;
    const int b   = blockIdx.x;
    const int beg = cbase[b];
    const int end = cbase[b + 1];

    if (tid < BROWS) hist[tid] = 0;
    __syncthreads();
    for (int e = beg + tid; e < end; e += 256) {
        int lr = (cv2[e].x >> 19) & (BROWS - 1);
        atomicAdd(&hist[lr], 1);
    }
    __syncthreads();
    const int v = (tid < BROWS) ? hist[tid] : 0;
    if (tid < BROWS) sc[tid] = v;
    __syncthreads();
    for (int off = 1; off < BROWS; off <<= 1) {
        int t = (tid < BROWS && tid >= off) ? sc[tid - off] : 0;
        __syncthreads();
        if (tid < BROWS) sc[tid] += t;
        __syncthreads();
    }
    if (tid < BROWS) {
        const int excl = sc[tid] - v;
        cur[tid] = excl;
        const int row = (b << BSHIFT) + tid;
        if (row < N) rowoff[row] = beg + excl;
    }
    if (b == nbuk - 1 && tid == 0) rowoff[N] = cbase[nbuk];
    __syncthreads();
    for (int e = beg + tid; e < end; e += 256) {
        int2 m  = cv2[e];
        int lr  = (m.x >> 19) & (BROWS - 1);
        int pos = beg + atomicAdd(&cur[lr], 1);
        cv2b[pos] = m;
    }
}

// ---------------------------------------------------------------------------
// Accumulate: one wave per output row, quarter-wave edge quads (round-8
// proven, at its structural floor: L2-miss path saturated ~3.6 TB/s).
// ---------------------------------------------------------------------------
__global__ __launch_bounds__(256) void raccum_kernel(
    const int2* __restrict__ cv2b, const int* __restrict__ rowoff,
    const unsigned short* __restrict__ xlinb, float* __restrict__ out, int N)
{
    const int lane = threadIdx.x & 63;
    const int r    = blockIdx.x * 4 + (threadIdx.x >> 6);
    if (r >= N) return;
    const int q  = lane >> 4;             // edge-in-quad 0..3
    const int fl = lane & 15;             // feature group: features fl*4..fl*4+3
    const int beg = rowoff[r];
    const int end = rowoff[r + 1];
    float a0 = 0.f, a1 = 0.f, a2 = 0.f, a3 = 0.f;
    int i = beg;
    for (; i + 16 <= end; i += 16) {
#pragma unroll
        for (int j = 0; j < 4; ++j) {
            const int2 m = cv2b[i + 4 * j + q];
            const unsigned slot = (unsigned)m.x & 0x7FFFFu;
            const ushort4 g = *(const ushort4*)(xlinb + ((size_t)slot << 6) + (fl << 2));
            const float v = __int_as_float(m.y);
            a0 = fmaf(v, bfbits2f(g.x), a0);
            a1 = fmaf(v, bfbits2f(g.y), a1);
            a2 = fmaf(v, bfbits2f(g.z), a2);
            a3 = fmaf(v, bfbits2f(g.w), a3);
        }
    }
    for (; i + 4 <= end; i += 4) {
        const int2 m = cv2b[i + q];
        const unsigned slot = (unsigned)m.x & 0x7FFFFu;
        const ushort4 g = *(const ushort4*)(xlinb + ((size_t)slot << 6) + (fl << 2));
        const float v = __int_as_float(m.y);
        a0 = fmaf(v, bfbits2f(g.x), a0);
        a1 = fmaf(v, bfbits2f(g.y), a1);
        a2 = fmaf(v, bfbits2f(g.z), a2);
        a3 = fmaf(v, bfbits2f(g.w), a3);
    }
    for (; i < end; ++i) {                // 1-3 trailing edges: quad group 0
        if (q == 0) {
            const int2 m = cv2b[i];
            const unsigned slot = (unsigned)m.x & 0x7FFFFu;
            const ushort4 g = *(const ushort4*)(xlinb + ((size_t)slot << 6) + (fl << 2));
            const float v = __int_as_float(m.y);
            a0 = fmaf(v, bfbits2f(g.x), a0);
            a1 = fmaf(v, bfbits2f(g.y), a1);
            a2 = fmaf(v, bfbits2f(g.z), a2);
            a3 = fmaf(v, bfbits2f(g.w), a3);
        }
    }
    a0 += __shfl_xor(a0, 16); a0 += __shfl_xor(a0, 32);
    a1 += __shfl_xor(a1, 16); a1 += __shfl_xor(a1, 32);
    a2 += __shfl_xor(a2, 16); a2 += __shfl_xor(a2, 32);
    a3 += __shfl_xor(a3, 16); a3 += __shfl_xor(a3, 32);
    if (q == 0) {
        float4 o; o.x = a0; o.y = a1; o.z = a2; o.w = a3;
        *(float4*)(out + (size_t)r * F_IN + (fl << 2)) = o;
    }
}

// ---------------------------------------------------------------------------
// Fallback path kernels (workspace too small): stats + VALU gemm + scatter.
// ---------------------------------------------------------------------------
__global__ __launch_bounds__(256) void stats_kernel(
    const float* __restrict__ a, float* __restrict__ stats, int N)
{
    __shared__ float ssum[256];
    __shared__ float ssq[256];
    const int tid = threadIdx.x;
    const int c   = tid & 63;
    int r         = blockIdx.x * 4 + (tid >> 6);
    const int rstride = gridDim.x * 4;
    float ps = 0.f, pq = 0.f;
    for (; r < N; r += rstride) {
        float v = a[(size_t)r * F_IN + c];
        ps += v;
        pq += v * v;
    }
    ssum[tid] = ps;
    ssq[tid]  = pq;
    __syncthreads();
    if (tid < 64) {
        float s = ssum[tid] + ssum[tid + 64] + ssum[tid + 128] + ssum[tid + 192];
        float q = ssq[tid]  + ssq[tid + 64]  + ssq[tid + 128]  + ssq[tid + 192];
        atomicAdd(&stats[tid], s);
        atomicAdd(&stats[64 + tid], q);
    }
}

__global__ __launch_bounds__(256) void gemm_kernel(
    const float* __restrict__ a, const float* __restrict__ stats,
    const float* __restrict__ gamma, const float* __restrict__ beta,
    const float* __restrict__ W, const float* __restrict__ b,
    __hip_bfloat16* __restrict__ xlinb, int N)
{
    __shared__ float xs[32][F_IN];
    const int tid = threadIdx.x;
    const int c   = tid & 63;

    const float invN  = 1.0f / (float)N;
    const float mean  = stats[c] * invN;
    const float var   = stats[64 + c] * invN - mean * mean;
    const float scale = rsqrtf(var + 1e-5f) * gamma[c];
    const float shift = beta[c];

    float wreg[F_IN];
#pragma unroll
    for (int k = 0; k < F_IN; ++k) wreg[k] = W[k * KF + tid];
    const float bias = b[tid];

    const int i0 = blockIdx.x * 32;

#pragma unroll
    for (int it = 0; it < 8; ++it) {
        int idx = tid + it * 256;
        int r   = idx >> 6;
        int row = i0 + r;
        float v = 0.f;
        if (row < N) {
            v = (a[(size_t)row * F_IN + c] - mean) * scale + shift;
            v = (v > 0.f) ? v : expm1f(v);
        }
        xs[r][c] = v;
    }
    __syncthreads();

    const int rmax = min(32, N - i0);
    for (int r = 0; r < rmax; ++r) {
        const float4* xsr = (const float4*)xs[r];
        float acc = bias;
#pragma unroll
        for (int k4 = 0; k4 < 16; ++k4) {
            float4 xv = xsr[k4];
            acc = fmaf(xv.x, wreg[k4 * 4 + 0], acc);
            acc = fmaf(xv.y, wreg[k4 * 4 + 1], acc);
            acc = fmaf(xv.z, wreg[k4 * 4 + 2], acc);
            acc = fmaf(xv.w, wreg[k4 * 4 + 3], acc);
        }
        xlinb[(size_t)(i0 + r) * KF + tid] = __float2bfloat16(acc);
    }
}

__global__ __launch_bounds__(256) void scatter_kernel(
    const float* __restrict__ vals, const int* __restrict__ rows,
    const int* __restrict__ cols, const unsigned short* __restrict__ xlinb,
    float* __restrict__ out, int N, int E)
{
    const int lane = threadIdx.x & 63;
    int e = blockIdx.x * 4 + (threadIdx.x >> 6);
    const int estride = gridDim.x * 4;
    for (; e < E; e += estride) {
        float v  = vals[e];
        int   r  = rows[e];
        int   cc = cols[e];
        int k = 0, n2 = cc;
        while (n2 >= N) { n2 -= N; ++k; }
        float x = bfbits2f(xlinb[(size_t)n2 * KF + k * 64 + lane]);
        atomicAdd(&out[(size_t)r * F_IN + lane], v * x);
    }
}

extern "C" void kernel_launch(void* const* d_in, const int* in_sizes, int n_in,
                              void* d_out, int out_size, void* d_ws, size_t ws_size,
                              hipStream_t stream)
{
    const float* a     = (const float*)d_in[0];
    const float* gamma = (const float*)d_in[1];
    const float* beta  = (const float*)d_in[2];
    const float* W     = (const float*)d_in[3];
    const float* b     = (const float*)d_in[4];
    const float* vals  = (const float*)d_in[5];
    const int*   rows  = (const int*)d_in[6];
    const int*   cols  = (const int*)d_in[7];
    float*       out   = (float*)d_out;

    const int N    = in_sizes[0] / F_IN;
    const int E    = in_sizes[5];
    const int nbuk = (N + BROWS - 1) >> BSHIFT;
    const int CHB  = (E + 4095) / 4096;       // chist blocks (K1)
    const int EB   = (E + BPB - 1) / BPB;     // binpass blocks (K3)
    const int GB   = (N + 63) / 64;           // gemm blocks (K3)

    // Workspace layout:
    //   [0, 1024)        stats (128 f32)
    //   [1024, +4352)    ccnt
    //   [.., +4352)      cbase (nbuk+1)
    //   [.., +4352)      ccur
    //   [.., +512)       scsh (scale[64], shift[64])
    //   [.., +32768)     Wp (bf16 B-fragments)
    //   [.., +4(N+1))    rowoff
    //   [.., +8E)        cv2   (64B-aligned)
    //   [.., +8E)        cv2b
    //   [.., +2*N*KF)    xlin  (bf16, 256B-aligned, linear layout slot*64+f)
    char*  base     = (char*)d_ws;
    size_t o_ccnt   = 1024;
    size_t o_cbase  = o_ccnt + 4352;
    size_t o_ccur   = o_cbase + 4352;
    size_t o_scsh   = o_ccur + 4352;
    size_t o_wp     = o_scsh + 512;
    size_t o_rowoff = o_wp + 32768;
    size_t o_cv2    = (o_rowoff + (size_t)(N + 1) * 4 + 63) & ~(size_t)63;
    size_t o_cv2b   = o_cv2 + (size_t)E * 8;
    size_t o_xlin   = (o_cv2b + (size_t)E * 8 + 255) & ~(size_t)255;
    size_t need     = o_xlin + (size_t)N * KF * 2;

    const bool use_csr = (ws_size >= need) && (nbuk <= MAXBUK) && (N < (1 << 17));

    float* stats = (float*)base;

    if (use_csr) {
        int*            ccnt   = (int*)(base + o_ccnt);
        int*            cbase  = (int*)(base + o_cbase);
        int*            ccur   = (int*)(base + o_ccur);
        float*          scsh   = (float*)(base + o_scsh);
        short*          Wp     = (short*)(base + o_wp);
        int*            rowoff = (int*)(base + o_rowoff);
        int2*           cv2    = (int2*)(base + o_cv2);
        int2*           cv2b   = (int2*)(base + o_cv2b);
        unsigned short* xlinb  = (unsigned short*)(base + o_xlin);

        hipMemsetAsync(d_ws, 0, o_cbase, stream);   // stats + ccnt

        k1_stats_chist<<<SB + CHB, 256, 0, stream>>>(a, stats, N, rows, ccnt, E, nbuk);
        k2_scan_wprep<<<9, 256, 0, stream>>>(ccnt, cbase, ccur, nbuk,
                                             stats, gamma, beta, W, scsh, Wp, N);
        k3_gemm_binpass<<<EB + GB, 256, 0, stream>>>(a, scsh, Wp, b, xlinb, N, EB,
                                                     vals, rows, cols, ccur, cv2, E, nbuk);
        fsort_kernel<<<nbuk, 256, 0, stream>>>(cv2, cbase, cv2b, rowoff, N, nbuk);
        raccum_kernel<<<(N + 3) / 4, 256, 0, stream>>>(cv2b, rowoff, xlinb, out, N);
    } else {
        __hip_bfloat16* xlinb = (__hip_bfloat16*)(base + 1024);
        hipMemsetAsync(d_ws, 0, 512, stream);
        hipMemsetAsync(d_out, 0, (size_t)out_size * sizeof(float), stream);
        stats_kernel<<<512, 256, 0, stream>>>(a, stats, N);
        gemm_kernel<<<(N + 31) / 32, 256, 0, stream>>>(a, stats, gamma, beta, W, b, xlinb, N);
        scatter_kernel<<<8192, 256, 0, stream>>>(vals, rows, cols,
                                                 (const unsigned short*)xlinb, out, N, E);
    }
}